// Round 25
// baseline (84.924 us; speedup 1.0000x reference)
//
#include <hip/hip_runtime.h>

#define NFREQ   257
#define NFRAMES 3751
#define NS      480000
#define HOP     128
#define WIN     512

#define NB      32
#define BN      128                 // frames per block
#define NFT     30                  // 30*128 = 3840 frames
#define STEPS   32                  // 2 fp * 16 k32
#define XWPITCH 272                 // 128 samples (256B) + 16B pad
#define XW_B    35632               // 131 rows * 272
#define WNYQ_B  2048                // 512 f32 weights
#define XGROUPS 2096

typedef __attribute__((ext_vector_type(8)))  short short8;
typedef __attribute__((ext_vector_type(16))) float f32x16;

__device__ __forceinline__ short f2bf(float f) {
    __bf16 b = (__bf16)f;
    return __builtin_bit_cast(short, b);
}
__device__ __forceinline__ float bf2f(short s) {
    unsigned int u = ((unsigned int)(unsigned short)s) << 16;
    return __builtin_bit_cast(float, u);
}

// ---- prep: bake 32-step A stream for 32x32x16 MFMA, WAVE-PRIVATE chunks.
// byte ob: step=ob>>14, w=(ob>>12)&3, pl=(ob>>11)&1, kh=(ob>>10)&1, lane=(ob>>4)&63.
// content: basis[pl, (step>>4)*128 + w*32 + (lane&31),
//                (step&15)*32 + kh*16 + (lane>>5)*8 .. +8]
// (A-frag for mfma_32x32x16_bf16: row=lane&31, k=(lane>>5)*8+j, K=16 per kh.)
// Lane l loads byte l*16 of a contiguous 1KB chunk -> coalesced dwordx4.
__global__ __launch_bounds__(256)
void prep_basis10(const float* __restrict__ basis,
                  short* __restrict__ abL, short* __restrict__ wnyqG) {
    int g = blockIdx.x * 256 + threadIdx.x;
    if (g < 32768) {
        int ob   = g * 16;
        int step = ob >> 14;                 // 0..31
        int w    = (ob >> 12) & 3;
        int pl   = (ob >> 11) & 1;
        int kh   = (ob >> 10) & 1;
        int lane = (ob >> 4) & 63;
        int fr   = (step >> 4) * 128 + w * 32 + (lane & 31);   // 0..255 < 257
        int k0   = (step & 15) * 32 + kh * 16 + (lane >> 5) * 8;
        const float4* p = reinterpret_cast<const float4*>(
            basis + ((size_t)(pl * NFREQ + fr)) * WIN + k0);
        float4 a0 = p[0], a1 = p[1];
        short8 v;
        v[0]=f2bf(a0.x); v[1]=f2bf(a0.y); v[2]=f2bf(a0.z); v[3]=f2bf(a0.w);
        v[4]=f2bf(a1.x); v[5]=f2bf(a1.y); v[6]=f2bf(a1.z); v[7]=f2bf(a1.w);
        *reinterpret_cast<short8*>(reinterpret_cast<char*>(abL) + ob) = v;
    } else if (g < 32832) {                  // nyq row: real plane row 256
        int j = g - 32768;
        const float4* p = reinterpret_cast<const float4*>(basis + (size_t)256 * WIN + j * 8);
        float4 a0 = p[0], a1 = p[1];
        short8 v;
        v[0]=f2bf(a0.x); v[1]=f2bf(a0.y); v[2]=f2bf(a0.z); v[3]=f2bf(a0.w);
        v[4]=f2bf(a1.x); v[5]=f2bf(a1.y); v[6]=f2bf(a1.z); v[7]=f2bf(a1.w);
        *reinterpret_cast<short8*>(wnyqG + j * 8) = v;
    }
}

// ---- main: 128f x 128t tile, wave 32f x 128t (4 tiles of 32x32), barrier-free;
// v_mfma_f32_32x32x16_bf16 (13% faster pipe than 16x16x32, m119 vs m06);
// A direct global->VGPR; X in LDS; nyq in the xv window; setprio cluster ----
__global__ __launch_bounds__(256, 2)
void stft_mfma_kernel(const float* __restrict__ x,
                      const short* __restrict__ abL,
                      const short* __restrict__ wnyqG,
                      float* __restrict__ out)
{
    __shared__ __align__(16) char smem[XW_B + WNYQ_B];   // 37680 B
    char* const xw   = smem;
    float* const wny = reinterpret_cast<float*>(smem + XW_B);

    const int tid  = threadIdx.x;
    const int wave = tid >> 6;          // 0..3 : freq stack (32 rows each)
    const int lane = tid & 63;
    const int l31  = lane & 31;
    const int lhi  = lane >> 5;         // 0..1 : k-half within fragment

    // bijective XCD chunk swizzle: 960 = 8 * 120
    const int logical = (blockIdx.x & 7) * 120 + (blockIdx.x >> 3);
    const int ft = logical % NFT;
    const int b  = logical / NFT;
    const int t0 = ft * BN;

    // per-lane A stream base for this wave
    const char* const aS = (const char*)abL + (wave << 12) + lane * 16;

    // nyq weights: bf16 global -> f32 LDS (512 values, 2/thread)
    {
        short a0 = wnyqG[tid * 2], a1 = wnyqG[tid * 2 + 1];
        wny[tid * 2]     = bf2f(a0);
        wny[tid * 2 + 1] = bf2f(a1);
    }

    // ---- prologue: fp32 x window -> bf16 LDS, padded rows, reflect edges ----
    {
        const float* __restrict__ xb = x + (size_t)b * NS;
        const int sbase = t0 * 128 - 256;
        #pragma unroll
        for (int i = 0; i < 9; ++i) {
            int g = tid + i * 256;
            if (g < XGROUPS) {
                int ix = sbase + g * 8;
                short8 v;
                if (ix >= 0 && ix + 8 <= NS) {
                    const float4* p = reinterpret_cast<const float4*>(xb + ix);
                    float4 a0 = p[0], a1 = p[1];
                    v[0]=f2bf(a0.x); v[1]=f2bf(a0.y); v[2]=f2bf(a0.z); v[3]=f2bf(a0.w);
                    v[4]=f2bf(a1.x); v[5]=f2bf(a1.y); v[6]=f2bf(a1.z); v[7]=f2bf(a1.w);
                } else {
                    #pragma unroll
                    for (int q = 0; q < 8; ++q) {
                        int idx = ix + q;
                        if (idx < 0) idx = -idx;
                        if (idx >= NS + 256) { v[q] = 0; continue; }
                        if (idx >= NS) idx = 2 * NS - 2 - idx;
                        v[q] = f2bf(xb[idx]);
                    }
                }
                *reinterpret_cast<short8*>(xw + (g >> 4) * XWPITCH + (g & 15) * 16) = v;
            }
        }
    }
    __syncthreads();    // the ONLY barrier: X window visibility

    f32x16 accR[4], accI[4];
    #pragma unroll
    for (int tt = 0; tt < 4; ++tt)
        #pragma unroll
        for (int e = 0; e < 16; ++e) { accR[tt][e] = 0.f; accI[tt][e] = 0.f; }

    // nyquist assignment: frame fl (0..127), window half h; one 8-chunk per step
    const int nfl = wave * 32 + l31;
    const int nh  = lhi;
    const int nyqXbase = (nfl + 2 * nh) * XWPITCH;
    const float* const nyqW = wny + nh * 256;
    float nacc = 0.f;

    short8 R0[2], I0[2], R1[2], I1[2];

    #define ALOAD(RS, IS, s)                                                        \
    {                                                                               \
        const char* p_ = aS + (size_t)(s) * 16384;                                  \
        (RS)[0] = *reinterpret_cast<const short8*>(p_);                             \
        (RS)[1] = *reinterpret_cast<const short8*>(p_ + 1024);                      \
        (IS)[0] = *reinterpret_cast<const short8*>(p_ + 2048);                      \
        (IS)[1] = *reinterpret_cast<const short8*>(p_ + 3072);                      \
    }

    // B-frag (32x32x16): col/frame = tt*32 + l31, k-byte = kh*32 + lhi*16
    #define COMPUTE(s, R, I)                                                        \
    {                                                                               \
        short8 xv[8];                                                               \
        {                                                                           \
            _Pragma("unroll")                                                       \
            for (int tt = 0; tt < 4; ++tt)                                          \
                _Pragma("unroll")                                                   \
                for (int kh = 0; kh < 2; ++kh) {                                    \
                    int r8 = ((s) & 15) * 64 + kh * 32 + lhi * 16;                  \
                    int T  = r8 + ((r8 >> 8) << 4);                                 \
                    xv[tt * 2 + kh] = *reinterpret_cast<const short8*>(             \
                        xw + (tt * 32 + l31) * XWPITCH + T);                        \
                }                                                                   \
        }                                                                           \
        {   /* nyquist chunk: executes while xv reads are in flight */              \
            short8 nx = *reinterpret_cast<const short8*>(                           \
                xw + nyqXbase + ((s) >> 4) * XWPITCH + ((s) & 15) * 16);            \
            const float* wrow = nyqW + (s) * 8;                                     \
            _Pragma("unroll")                                                       \
            for (int q = 0; q < 8; ++q)                                             \
                nacc = fmaf(bf2f(nx[q]), wrow[q], nacc);                            \
        }                                                                           \
        __builtin_amdgcn_s_setprio(1);                                              \
        _Pragma("unroll")                                                           \
        for (int tt = 0; tt < 4; ++tt) {                                            \
            accR[tt] = __builtin_amdgcn_mfma_f32_32x32x16_bf16(                     \
                (R)[0], xv[tt * 2 + 0], accR[tt], 0, 0, 0);                         \
            accR[tt] = __builtin_amdgcn_mfma_f32_32x32x16_bf16(                     \
                (R)[1], xv[tt * 2 + 1], accR[tt], 0, 0, 0);                         \
            accI[tt] = __builtin_amdgcn_mfma_f32_32x32x16_bf16(                     \
                (I)[0], xv[tt * 2 + 0], accI[tt], 0, 0, 0);                         \
            accI[tt] = __builtin_amdgcn_mfma_f32_32x32x16_bf16(                     \
                (I)[1], xv[tt * 2 + 1], accI[tt], 0, 0, 0);                         \
        }                                                                           \
        __builtin_amdgcn_s_setprio(0);                                              \
    }

    // C/D layout (32x32, m74/m101): col = lane&31 (frame),
    // row = (reg&3) + 8*(reg>>2) + 4*(lane>>5) (freq)
    #define EPILOGUE(fp)                                                            \
    {                                                                               \
        float* ob = out + (size_t)b * NFREQ * NFRAMES;                              \
        const int fb = (fp) * 128 + wave * 32 + 4 * lhi;                            \
        _Pragma("unroll")                                                           \
        for (int tt = 0; tt < 4; ++tt) {                                            \
            int t = t0 + tt * 32 + l31;                                             \
            if (t < NFRAMES) {                                                      \
                _Pragma("unroll")                                                   \
                for (int r = 0; r < 16; ++r) {                                      \
                    int f = fb + (r & 3) + 8 * (r >> 2);                            \
                    float vr = accR[tt][r], vi = accI[tt][r];                       \
                    ob[(size_t)f * NFRAMES + t] =                                   \
                        __builtin_amdgcn_sqrtf(vr * vr + vi * vi);                  \
                }                                                                   \
            }                                                                       \
            _Pragma("unroll")                                                       \
            for (int e = 0; e < 16; ++e) { accR[tt][e] = 0.f; accI[tt][e] = 0.f; }  \
        }                                                                           \
    }

    // prologue: step 0 into set0
    ALOAD(R0, I0, 0);

    #pragma unroll 1
    for (int s = 0; s < STEPS; s += 2) {
        ALOAD(R1, I1, s + 1);                 // prefetch odd step
        COMPUTE(s, R0, I0);
        if (s + 2 < STEPS) ALOAD(R0, I0, s + 2);   // prefetch next even step
        COMPUTE(s + 1, R1, I1);
        if ((s & 15) == 14) EPILOGUE(s >> 4);      // after steps 15 and 31
    }

    // ---- nyquist reduce + store (f=256) ----
    {
        nacc += __shfl_xor(nacc, 32);
        int t = t0 + nfl;
        if (nh == 0 && t < NFRAMES)
            out[((size_t)b * NFREQ + 256) * NFRAMES + t] = fabsf(nacc);
    }
}

extern "C" void kernel_launch(void* const* d_in, const int* in_sizes, int n_in,
                              void* d_out, int out_size, void* d_ws, size_t ws_size,
                              hipStream_t stream) {
    const float* x     = (const float*)d_in[0];
    const float* basis = (const float*)d_in[1];
    float* out = (float*)d_out;

    short* abL   = (short*)d_ws;                      // 32 steps x 16KB = 512KB
    short* wnyqG = abL + 262144;                      // 512 bf16

    prep_basis10<<<dim3(129), 256, 0, stream>>>(basis, abL, wnyqG);
    stft_mfma_kernel<<<dim3(NFT * NB), 256, 0, stream>>>(x, abL, wnyqG, out);  // 960 blocks
}

// Round 26
// 73.428 us; speedup vs baseline: 1.1566x; 1.1566x over previous
//
#include <hip/hip_runtime.h>

#define NFREQ   257
#define NFRAMES 3751
#define NS      480000
#define HOP     128
#define WIN     512

#define NB      32
#define BN      128                 // frames per block
#define NFT     30                  // 30*128 = 3840 frames
#define STEPS   32                  // 2 fp * 16 k32
#define XWPITCH 272                 // 128 samples (256B) + 16B pad
#define XW_B    35632               // 131 rows * 272
#define WNYQ_B  2048                // 512 f32 weights
#define XGROUPS 2096

typedef __attribute__((ext_vector_type(8))) short short8;
typedef __attribute__((ext_vector_type(4))) float f32x4;

__device__ __forceinline__ short f2bf(float f) {
    __bf16 b = (__bf16)f;
    return __builtin_bit_cast(short, b);
}
__device__ __forceinline__ float bf2f(short s) {
    unsigned int u = ((unsigned int)(unsigned short)s) << 16;
    return __builtin_bit_cast(float, u);
}

// ---- prep: bake 32-step A stream, WAVE-PRIVATE, LANE-LINEAR chunks.
// byte ob: step=ob>>14, w=(ob>>12)&3, pl=(ob>>11)&1, m=(ob>>10)&1, lane=(ob>>4)&63.
// content: basis[pl, (step>>4)*128 + w*32 + m*16 + (lane&15),
//                (step&15)*32 + (lane>>4)*8 .. +8]
// Direct-A read: lane l loads byte l*16 of a contiguous 1KB chunk ->
// ONE coalesced global_load_dwordx4 per chunk, L2-resident.
__global__ __launch_bounds__(256)
void prep_basis9(const float* __restrict__ basis,
                 short* __restrict__ abL, short* __restrict__ wnyqG) {
    int g = blockIdx.x * 256 + threadIdx.x;
    if (g < 32768) {
        int ob   = g * 16;
        int step = ob >> 14;                 // 0..31
        int w    = (ob >> 12) & 3;
        int pl   = (ob >> 11) & 1;
        int m    = (ob >> 10) & 1;
        int lane = (ob >> 4) & 63;
        int l15  = lane & 15;
        int lgrp = lane >> 4;
        int fr   = (step >> 4) * 128 + w * 32 + m * 16 + l15;   // 0..255 < 257
        int k0   = (step & 15) * 32 + lgrp * 8;
        const float4* p = reinterpret_cast<const float4*>(
            basis + ((size_t)(pl * NFREQ + fr)) * WIN + k0);
        float4 a0 = p[0], a1 = p[1];
        short8 v;
        v[0]=f2bf(a0.x); v[1]=f2bf(a0.y); v[2]=f2bf(a0.z); v[3]=f2bf(a0.w);
        v[4]=f2bf(a1.x); v[5]=f2bf(a1.y); v[6]=f2bf(a1.z); v[7]=f2bf(a1.w);
        *reinterpret_cast<short8*>(reinterpret_cast<char*>(abL) + ob) = v;
    } else if (g < 32832) {                  // nyq row: real plane row 256
        int j = g - 32768;
        const float4* p = reinterpret_cast<const float4*>(basis + (size_t)256 * WIN + j * 8);
        float4 a0 = p[0], a1 = p[1];
        short8 v;
        v[0]=f2bf(a0.x); v[1]=f2bf(a0.y); v[2]=f2bf(a0.z); v[3]=f2bf(a0.w);
        v[4]=f2bf(a1.x); v[5]=f2bf(a1.y); v[6]=f2bf(a1.z); v[7]=f2bf(a1.w);
        *reinterpret_cast<short8*>(wnyqG + j * 8) = v;
    }
}

// ---- main: 128f x 128t tile, wave 32f x 128t; barrier-free K-loop;
// A DIRECT global->VGPR (register double-buffer); X in LDS (staged once);
// nyq chunk placed in the xv lgkm window; setprio around MFMA cluster ----
__global__ __launch_bounds__(256, 2)
void stft_mfma_kernel(const float* __restrict__ x,
                      const short* __restrict__ abL,
                      const short* __restrict__ wnyqG,
                      float* __restrict__ out)
{
    __shared__ __align__(16) char smem[XW_B + WNYQ_B];   // 37680 B
    char* const xw   = smem;
    float* const wny = reinterpret_cast<float*>(smem + XW_B);

    const int tid  = threadIdx.x;
    const int wave = tid >> 6;          // 0..3 : freq stack (32 rows each)
    const int lane = tid & 63;
    const int lgrp = lane >> 4;
    const int l15  = lane & 15;

    // bijective XCD chunk swizzle: 960 = 8 * 120
    const int logical = (blockIdx.x & 7) * 120 + (blockIdx.x >> 3);
    const int ft = logical % NFT;
    const int b  = logical / NFT;
    const int t0 = ft * BN;

    // per-lane A stream base for this wave
    const char* const aS = (const char*)abL + (wave << 12) + lane * 16;

    // nyq weights: bf16 global -> f32 LDS (512 values, 2/thread)
    {
        short a0 = wnyqG[tid * 2], a1 = wnyqG[tid * 2 + 1];
        wny[tid * 2]     = bf2f(a0);
        wny[tid * 2 + 1] = bf2f(a1);
    }

    // ---- prologue: fp32 x window -> bf16 LDS, padded rows, reflect edges ----
    {
        const float* __restrict__ xb = x + (size_t)b * NS;
        const int sbase = t0 * 128 - 256;
        #pragma unroll
        for (int i = 0; i < 9; ++i) {
            int g = tid + i * 256;
            if (g < XGROUPS) {
                int ix = sbase + g * 8;
                short8 v;
                if (ix >= 0 && ix + 8 <= NS) {
                    const float4* p = reinterpret_cast<const float4*>(xb + ix);
                    float4 a0 = p[0], a1 = p[1];
                    v[0]=f2bf(a0.x); v[1]=f2bf(a0.y); v[2]=f2bf(a0.z); v[3]=f2bf(a0.w);
                    v[4]=f2bf(a1.x); v[5]=f2bf(a1.y); v[6]=f2bf(a1.z); v[7]=f2bf(a1.w);
                } else {
                    #pragma unroll
                    for (int q = 0; q < 8; ++q) {
                        int idx = ix + q;
                        if (idx < 0) idx = -idx;
                        if (idx >= NS + 256) { v[q] = 0; continue; }
                        if (idx >= NS) idx = 2 * NS - 2 - idx;
                        v[q] = f2bf(xb[idx]);
                    }
                }
                *reinterpret_cast<short8*>(xw + (g >> 4) * XWPITCH + (g & 15) * 16) = v;
            }
        }
    }
    __syncthreads();    // the ONLY barrier: X window visibility

    f32x4 accR[2][8], accI[2][8];
    #pragma unroll
    for (int m = 0; m < 2; ++m)
        #pragma unroll
        for (int n = 0; n < 8; ++n) {
            accR[m][n] = f32x4{0.f,0.f,0.f,0.f};
            accI[m][n] = f32x4{0.f,0.f,0.f,0.f};
        }

    // nyquist assignment: frame fl (0..127), window half h; one 8-chunk per step
    const int nfl = wave * 32 + (lane & 31);
    const int nh  = lane >> 5;
    const int nyqXbase = (nfl + 2 * nh) * XWPITCH;
    const float* const nyqW = wny + nh * 256;
    float nacc = 0.f;

    short8 R0[2], I0[2], R1[2], I1[2];

    #define ALOAD(RS, IS, s)                                                        \
    {                                                                               \
        const char* p_ = aS + (size_t)(s) * 16384;                                  \
        (RS)[0] = *reinterpret_cast<const short8*>(p_);                             \
        (RS)[1] = *reinterpret_cast<const short8*>(p_ + 1024);                      \
        (IS)[0] = *reinterpret_cast<const short8*>(p_ + 2048);                      \
        (IS)[1] = *reinterpret_cast<const short8*>(p_ + 3072);                      \
    }

    // xv issues first; nyq (1 lds + 16 VALU) fills the lgkm window; then the
    // MFMA cluster under raised priority (T5: barrier-free waves are role-diverse)
    #define COMPUTE(s, R, I)                                                        \
    {                                                                               \
        short8 xv[8];                                                               \
        {                                                                           \
            int r8 = ((s) & 15) * 64 + lgrp * 16;                                   \
            int T  = r8 + ((r8 >> 8) << 4);                                         \
            const char* xwl = xw + l15 * XWPITCH + T;                               \
            _Pragma("unroll")                                                       \
            for (int nt = 0; nt < 8; ++nt)                                          \
                xv[nt] = *reinterpret_cast<const short8*>(xwl + nt * (16 * XWPITCH)); \
        }                                                                           \
        {   /* nyquist chunk: executes while xv reads are in flight */              \
            short8 nx = *reinterpret_cast<const short8*>(                           \
                xw + nyqXbase + ((s) >> 4) * XWPITCH + ((s) & 15) * 16);            \
            const float* wrow = nyqW + (s) * 8;                                     \
            _Pragma("unroll")                                                       \
            for (int q = 0; q < 8; ++q)                                             \
                nacc = fmaf(bf2f(nx[q]), wrow[q], nacc);                            \
        }                                                                           \
        __builtin_amdgcn_s_setprio(1);                                              \
        _Pragma("unroll")                                                           \
        for (int m = 0; m < 2; ++m)                                                 \
            _Pragma("unroll")                                                       \
            for (int nt = 0; nt < 8; ++nt) {                                        \
                accR[m][nt] = __builtin_amdgcn_mfma_f32_16x16x32_bf16(              \
                    (R)[m], xv[nt], accR[m][nt], 0, 0, 0);                          \
                accI[m][nt] = __builtin_amdgcn_mfma_f32_16x16x32_bf16(              \
                    (I)[m], xv[nt], accI[m][nt], 0, 0, 0);                          \
            }                                                                       \
        __builtin_amdgcn_s_setprio(0);                                              \
    }

    #define EPILOGUE(fp)                                                            \
    {                                                                               \
        float* ob = out + (size_t)b * NFREQ * NFRAMES;                              \
        const int fb = (fp) * 128 + wave * 32 + lgrp * 4;                           \
        const int tb = t0 + l15;                                                    \
        _Pragma("unroll")                                                           \
        for (int m = 0; m < 2; ++m)                                                 \
            _Pragma("unroll")                                                       \
            for (int nt = 0; nt < 8; ++nt) {                                        \
                int t = tb + nt * 16;                                               \
                if (t < NFRAMES) {                                                  \
                    _Pragma("unroll")                                               \
                    for (int r = 0; r < 4; ++r) {                                   \
                        int f = fb + m * 16 + r;                                    \
                        float vr = accR[m][nt][r], vi = accI[m][nt][r];             \
                        ob[(size_t)f * NFRAMES + t] =                               \
                            __builtin_amdgcn_sqrtf(vr * vr + vi * vi);              \
                    }                                                               \
                }                                                                   \
                accR[m][nt] = f32x4{0.f,0.f,0.f,0.f};                               \
                accI[m][nt] = f32x4{0.f,0.f,0.f,0.f};                               \
            }                                                                       \
    }

    // prologue: step 0 into set0
    ALOAD(R0, I0, 0);

    #pragma unroll 1
    for (int s = 0; s < STEPS; s += 2) {
        ALOAD(R1, I1, s + 1);                 // prefetch odd step
        COMPUTE(s, R0, I0);
        if (s + 2 < STEPS) ALOAD(R0, I0, s + 2);   // prefetch next even step
        COMPUTE(s + 1, R1, I1);
        if ((s & 15) == 14) EPILOGUE(s >> 4);      // after steps 15 and 31
    }

    // ---- nyquist reduce + store (f=256) ----
    {
        nacc += __shfl_xor(nacc, 32);
        int t = t0 + nfl;
        if (nh == 0 && t < NFRAMES)
            out[((size_t)b * NFREQ + 256) * NFRAMES + t] = fabsf(nacc);
    }
}

extern "C" void kernel_launch(void* const* d_in, const int* in_sizes, int n_in,
                              void* d_out, int out_size, void* d_ws, size_t ws_size,
                              hipStream_t stream) {
    const float* x     = (const float*)d_in[0];
    const float* basis = (const float*)d_in[1];
    float* out = (float*)d_out;

    short* abL   = (short*)d_ws;                      // 32 steps x 16KB = 512KB
    short* wnyqG = abL + 262144;                      // 512 bf16

    prep_basis9<<<dim3(129), 256, 0, stream>>>(basis, abL, wnyqG);
    stft_mfma_kernel<<<dim3(NFT * NB), 256, 0, stream>>>(x, abL, wnyqG, out);  // 960 blocks
}